// Round 5
// baseline (222.037 us; speedup 1.0000x reference)
//
#include <hip/hip_runtime.h>

#define A_N 8192
#define OBS_D 520
#define EMB 64
#define HID 128
#define NACT 6
#define SPLIT 16

typedef short bf16x8 __attribute__((ext_vector_type(8)));
typedef _Float16 half8 __attribute__((ext_vector_type(8)));
typedef float f32x4 __attribute__((ext_vector_type(4)));
typedef unsigned short u16;
typedef unsigned int u32;

#define MFMA_BF(a,b,c) __builtin_amdgcn_mfma_f32_16x16x32_bf16(a,b,c,0,0,0)
#define MFMA_FH(a,b,c) __builtin_amdgcn_mfma_f32_16x16x32_f16(a,b,c,0,0,0)

__device__ inline u32 fbits(float f){ union{float f; u32 u;}v; v.f=f; return v.u; }
__device__ inline float fval(u32 u){ union{u32 u; float f;}v; v.u=u; return v.f; }
__device__ inline u16 f2bf(float f){ u32 u=fbits(f); u += 0x7fffu + ((u>>16)&1u); return (u16)(u>>16); }
// pack trunc-bf16(pe) low, trunc-bf16(po) high
__device__ inline u32 pk_bf(float pe, float po){
  return __builtin_amdgcn_perm(fbits(po), fbits(pe), 0x07060302u);
}
__device__ inline float sigmoidf_fast(float x){
  x = fminf(fmaxf(x, -30.f), 30.f);
  return 1.f / (1.f + __expf(-x));
}
__device__ inline float tanhf_fast(float x){
  x = fminf(fmaxf(x, -15.f), 15.f);
  float e = __expf(-2.f*x);
  return (1.f - e) / (1.f + e);
}

// exp2 constant: (1/sqrt(64)) * log2(e)
#define EXP2C 0.18033688011112042f

// ---------------------------------------------------------------------------
// kPrep: coalesced LDS-transpose of all weights. 40 blocks x 256.
// ---------------------------------------------------------------------------
__global__ __launch_bounds__(256) void kPrep(
    const float* __restrict__ Wg, const float* __restrict__ Wir,
    const float* __restrict__ Wiz, const float* __restrict__ Win,
    const float* __restrict__ Whr, const float* __restrict__ Whz,
    const float* __restrict__ Whn, const float* __restrict__ W1,
    const float* __restrict__ W2, const float* __restrict__ Wb,
    _Float16* __restrict__ WT, _Float16* __restrict__ W1T,
    _Float16* __restrict__ W2T, u16* __restrict__ WbT)
{
  __shared__ float tile[64][65];
  const int t = threadIdx.x, b = blockIdx.x;

  const float* src; int k0, c0, srcStride, kValid;
  if (b < 28) {
    const int mi = b >> 2, tl = b & 3;
    src = mi==0?Wg: mi==1?Wir: mi==2?Wiz: mi==3?Win: mi==4?Whr: mi==5?Whz: Whn;
    k0 = (tl >> 1) * 64; c0 = (tl & 1) * 64; srcStride = 128; kValid = 128;
  } else if (b < 37) {
    src = W1; k0 = (b - 28) * 64; c0 = 0; srcStride = 64; kValid = OBS_D;
  } else if (b < 38) {
    src = W2; k0 = 0; c0 = 0; srcStride = 64; kValid = 64;
  } else {
    src = Wb; k0 = (b - 38) * 64; c0 = 0; srcStride = 64; kValid = 128;
  }
  #pragma unroll
  for (int i = 0; i < 16; i++) {
    const int idx = i * 256 + t;
    const int rr = idx >> 6, cc = idx & 63;   // rr = k-local, cc = c-local
    tile[rr][cc] = (k0 + rr < kValid) ? src[(size_t)(k0 + rr) * srcStride + c0 + cc] : 0.f;
  }
  __syncthreads();
  if (b < 28) {
    const int mi = b >> 2;
    _Float16* dst = WT + (size_t)mi * 16384;
    #pragma unroll
    for (int i = 0; i < 16; i++) {
      const int idx = i * 256 + t;
      const int rr = idx >> 6, cc = idx & 63;  // rr = c-local, cc = k-local
      dst[(size_t)(c0 + rr) * 128 + k0 + cc] = (_Float16)tile[cc][rr];
    }
  } else if (b < 37) {
    #pragma unroll
    for (int i = 0; i < 16; i++) {
      const int idx = i * 256 + t;
      const int rr = idx >> 6, cc = idx & 63;
      if (k0 + cc < 544)
        W1T[(size_t)rr * 544 + k0 + cc] = (_Float16)tile[cc][rr];
    }
  } else if (b < 38) {
    #pragma unroll
    for (int i = 0; i < 16; i++) {
      const int idx = i * 256 + t;
      const int rr = idx >> 6, cc = idx & 63;
      W2T[(size_t)rr * 64 + cc] = (_Float16)tile[cc][rr];
    }
  } else {
    #pragma unroll
    for (int i = 0; i < 16; i++) {
      const int idx = i * 256 + t;
      const int rr = idx >> 6, cc = idx & 63;
      WbT[(size_t)rr * 128 + k0 + cc] = f2bf(tile[cc][rr]);
    }
  }
}

// ---------------------------------------------------------------------------
// kA2: bp = bf16(beliefs@Wb + bb), row-major [8192][64] + transposed [64][8192].
// ---------------------------------------------------------------------------
__global__ __launch_bounds__(256) void kA2(
    const float* __restrict__ beliefs, const u16* __restrict__ WbT,
    const float* __restrict__ bb, u16* __restrict__ bp, u16* __restrict__ bpT)
{
  const int lane = threadIdx.x & 63, wid = threadIdx.x >> 6;
  const int m = lane & 15, quad = lane >> 4;
  const int r0 = blockIdx.x * 64 + wid * 16;
  f32x4 c[4];
  #pragma unroll
  for (int ct = 0; ct < 4; ct++) c[ct] = (f32x4){0.f,0.f,0.f,0.f};

  #pragma unroll
  for (int s = 0; s < 4; s++) {
    const int k0 = s*32;
    const float* ap = beliefs + (size_t)(r0+m)*HID + k0 + quad*8;
    float4 a0 = *(const float4*)ap;
    float4 a1 = *(const float4*)(ap + 4);
    union { u16 e[8]; bf16x8 v; } av;
    av.e[0]=f2bf(a0.x); av.e[1]=f2bf(a0.y); av.e[2]=f2bf(a0.z); av.e[3]=f2bf(a0.w);
    av.e[4]=f2bf(a1.x); av.e[5]=f2bf(a1.y); av.e[6]=f2bf(a1.z); av.e[7]=f2bf(a1.w);
    #pragma unroll
    for (int ct = 0; ct < 4; ct++) {
      bf16x8 bw = *(const bf16x8*)(WbT + (size_t)(ct*16+m)*128 + k0 + quad*8);
      c[ct] = MFMA_BF(av.v, bw, c[ct]);
    }
  }
  #pragma unroll
  for (int ct = 0; ct < 4; ct++) {
    const int col = ct*16 + m;
    const float bbv = bb[col];
    u16 e[4];
    #pragma unroll
    for (int r = 0; r < 4; r++) e[r] = f2bf(c[ct][r] + bbv);
    #pragma unroll
    for (int r = 0; r < 4; r++)
      bp[(size_t)(r0 + quad*4 + r)*EMB + col] = e[r];
    uint2 pkv;
    pkv.x = (u32)e[0] | ((u32)e[1] << 16);
    pkv.y = (u32)e[2] | ((u32)e[3] << 16);
    *(uint2*)(bpT + (size_t)col*A_N + r0 + quad*4) = pkv;
  }
}

// ---------------------------------------------------------------------------
// kM: blocks 0..127 = obs-MLP; blocks 128..1151 = flash attention.
// Attention: S^T = K·Q^T; P goes through a wave-private DOUBLE-BUFFERED LDS
// round-trip, software-pipelined one tile deep: iter t writes P(t) and runs
// PV(t-1) on P(t-1). In-order DS within a wave guarantees write(t-1) is
// visible to read(t-1); no barriers, no manual waitcnt — compiler inserts
// fine-grained lgkmcnt/vmcnt only at the consuming MFMAs.
// ---------------------------------------------------------------------------
__global__ __launch_bounds__(256) void kM(
    const u16* __restrict__ bp, const u16* __restrict__ bpT,
    u16* __restrict__ ctxp, float* __restrict__ sums,
    const float* __restrict__ obs, const _Float16* __restrict__ W1T,
    const float* __restrict__ b1, const _Float16* __restrict__ W2T,
    const float* __restrict__ b2, _Float16* __restrict__ h2f)
{
  __shared__ __align__(16) u16 P[4][2][2][16*72];   // [wid][buf][f] — 36864 B
  const int lane = threadIdx.x & 63;
  const int wid  = threadIdx.x >> 6;
  const int m = lane & 15, quad = lane >> 4;

  if (blockIdx.x >= 128) {
    // ------------------------- attention -------------------------
    const int w = (blockIdx.x - 128) * 4 + wid;
    const int split = w >> 8;
    const int qt = w & 255;
    const int q0 = qt * 32;

    bf16x8 qa[2][2];
    #pragma unroll
    for (int f = 0; f < 2; f++) {
      const u16* qr = bp + (size_t)(q0 + f*16 + m)*EMB + quad*8;
      qa[f][0] = *(const bf16x8*)(qr);
      qa[f][1] = *(const bf16x8*)(qr + 32);
    }
    f32x4 oacc[2][4];
    #pragma unroll
    for (int f = 0; f < 2; f++)
      #pragma unroll
      for (int d = 0; d < 4; d++) oacc[f][d] = (f32x4){0.f,0.f,0.f,0.f};
    float rowsum[2] = {0.f, 0.f};

    const int kbeg = split * (A_N / SPLIT);
    const int NT = (A_N / SPLIT) / 64;   // 8 tiles

    bf16x8 kb[4][2];
    #pragma unroll
    for (int jt = 0; jt < 4; jt++) {
      const u16* kr = bp + (size_t)(kbeg + jt*16 + m)*EMB + quad*8;
      kb[jt][0] = *(const bf16x8*)(kr);
      kb[jt][1] = *(const bf16x8*)(kr + 32);
    }

    // QK + exp + mask + P-write for tile base k0 into buffer `buf`
    auto QKW = [&](int k0, int buf) {
      #pragma unroll
      for (int jt = 0; jt < 4; jt++) {
        #pragma unroll
        for (int f = 0; f < 2; f++) {
          f32x4 s = (f32x4){0.f,0.f,0.f,0.f};
          s = MFMA_BF(kb[jt][0], qa[f][0], s);
          s = MFMA_BF(kb[jt][1], qa[f][1], s);
          float p0 = __builtin_amdgcn_exp2f(s[0]*EXP2C);
          float p1 = __builtin_amdgcn_exp2f(s[1]*EXP2C);
          float p2 = __builtin_amdgcn_exp2f(s[2]*EXP2C);
          float p3 = __builtin_amdgcn_exp2f(s[3]*EXP2C);
          if ((k0 + jt*16) == (q0 + f*16)) {   // wave-uniform diag tile
            const int jl = quad*4;
            if (jl + 0 == m) p0 = 0.f;
            if (jl + 1 == m) p1 = 0.f;
            if (jl + 2 == m) p2 = 0.f;
            if (jl + 3 == m) p3 = 0.f;
          }
          rowsum[f] += (p0 + p1) + (p2 + p3);
          uint2 pkv; pkv.x = pk_bf(p0, p1); pkv.y = pk_bf(p2, p3);
          // P_lds[q=m][j = jt*16 + quad*4 .. +3]
          *(uint2*)&P[wid][buf][f][m*72 + jt*16 + quad*4] = pkv;
        }
      }
    };
    // PV for tile base kp, reading buffer `buf`
    auto PV = [&](int kp, int buf) {
      bf16x8 pa[2][2];
      #pragma unroll
      for (int f = 0; f < 2; f++) {
        pa[f][0] = *(const bf16x8*)&P[wid][buf][f][m*72 + quad*8];
        pa[f][1] = *(const bf16x8*)&P[wid][buf][f][m*72 + 32 + quad*8];
      }
      #pragma unroll
      for (int dtt = 0; dtt < 4; dtt++) {
        const u16* vr = bpT + (size_t)(dtt*16+m)*A_N + kp + quad*8;
        const bf16x8 vb0 = *(const bf16x8*)(vr);
        const bf16x8 vb1 = *(const bf16x8*)(vr + 32);
        #pragma unroll
        for (int f = 0; f < 2; f++) {
          oacc[f][dtt] = MFMA_BF(pa[f][0], vb0, oacc[f][dtt]);
          oacc[f][dtt] = MFMA_BF(pa[f][1], vb1, oacc[f][dtt]);
        }
      }
    };

    QKW(kbeg, 0);
    // prefetch K(1)
    #pragma unroll
    for (int jt = 0; jt < 4; jt++) {
      const u16* kr = bp + (size_t)(kbeg + 64 + jt*16 + m)*EMB + quad*8;
      kb[jt][0] = *(const bf16x8*)(kr);
      kb[jt][1] = *(const bf16x8*)(kr + 32);
    }
    for (int t = 1; t < NT; t++) {
      const int kc = kbeg + t*64;
      QKW(kc, t & 1);
      if (t + 1 < NT) {
        #pragma unroll
        for (int jt = 0; jt < 4; jt++) {
          const u16* kr = bp + (size_t)(kc + 64 + jt*16 + m)*EMB + quad*8;
          kb[jt][0] = *(const bf16x8*)(kr);
          kb[jt][1] = *(const bf16x8*)(kr + 32);
        }
      }
      PV(kc - 64, (t - 1) & 1);
    }
    PV(kbeg + (NT-1)*64, (NT-1) & 1);

    // rowsum for query q = m: reduce across the 4 quads
    #pragma unroll
    for (int f = 0; f < 2; f++) {
      float v = rowsum[f];
      v += __shfl_xor(v, 16, 64);
      v += __shfl_xor(v, 32, 64);
      rowsum[f] = v;
    }
    if (lane < 16) {
      sums[(size_t)split*A_N + q0 + lane]      = rowsum[0];
      sums[(size_t)split*A_N + q0 + 16 + lane] = rowsum[1];
    }
    // oacc[f][dtt][r] = ctx[q = q0+f*16+quad*4+r][d = dtt*16+m]
    #pragma unroll
    for (int f = 0; f < 2; f++) {
      const size_t base = ((size_t)split*A_N + q0 + f*16) * EMB;
      #pragma unroll
      for (int dtt = 0; dtt < 4; dtt++)
        #pragma unroll
        for (int r = 0; r < 4; r++)
          ctxp[base + (size_t)(quad*4+r)*EMB + dtt*16 + m] = f2bf(oacc[f][dtt][r]);
    }
  } else {
    // ------------------------- obs-MLP -------------------------
    const int r0 = blockIdx.x * 64 + wid * 16;
    f32x4 oa[4];
    #pragma unroll
    for (int ct = 0; ct < 4; ct++) oa[ct] = (f32x4){0.f,0.f,0.f,0.f};

    for (int s = 0; s < 17; s++) {
      const int k0 = s * 32;
      union { _Float16 e[8]; half8 v; } af;
      if (s < 16) {
        const float* ap = obs + (size_t)(r0+m)*OBS_D + k0 + quad*8;
        float4 a0 = *(const float4*)ap;
        float4 a1 = *(const float4*)(ap + 4);
        af.e[0]=(_Float16)a0.x; af.e[1]=(_Float16)a0.y; af.e[2]=(_Float16)a0.z; af.e[3]=(_Float16)a0.w;
        af.e[4]=(_Float16)a1.x; af.e[5]=(_Float16)a1.y; af.e[6]=(_Float16)a1.z; af.e[7]=(_Float16)a1.w;
      } else {
        #pragma unroll
        for (int j = 0; j < 8; j++) af.e[j] = (_Float16)0.f;
        if (quad == 0) {
          const float* ap = obs + (size_t)(r0+m)*OBS_D + 512;
          float4 a0 = *(const float4*)ap;
          float4 a1 = *(const float4*)(ap + 4);
          af.e[0]=(_Float16)a0.x; af.e[1]=(_Float16)a0.y; af.e[2]=(_Float16)a0.z; af.e[3]=(_Float16)a0.w;
          af.e[4]=(_Float16)a1.x; af.e[5]=(_Float16)a1.y; af.e[6]=(_Float16)a1.z; af.e[7]=(_Float16)a1.w;
        }
      }
      #pragma unroll
      for (int ct = 0; ct < 4; ct++) {
        half8 bw = *(const half8*)(W1T + (size_t)(ct*16+m)*544 + k0 + quad*8);
        oa[ct] = MFMA_FH(af.v, bw, oa[ct]);
      }
    }
    _Float16* H1 = (_Float16*)&P[wid][0][0][0];
    #pragma unroll
    for (int ct = 0; ct < 4; ct++) {
      const float b1v = b1[ct*16 + m];
      #pragma unroll
      for (int r = 0; r < 4; r++) {
        float v = fmaxf(oa[ct][r] + b1v, 0.f);
        H1[(quad*4+r)*72 + ct*16 + m] = (_Float16)v;
      }
    }
    __syncthreads();   // MLP blocks are uniform; orders H1 write -> read
    f32x4 ob[4];
    #pragma unroll
    for (int ct = 0; ct < 4; ct++) ob[ct] = (f32x4){0.f,0.f,0.f,0.f};
    #pragma unroll
    for (int s2 = 0; s2 < 2; s2++) {
      half8 ah = *(const half8*)(H1 + m*72 + s2*32 + quad*8);
      #pragma unroll
      for (int ct = 0; ct < 4; ct++) {
        half8 bw = *(const half8*)(W2T + (size_t)(ct*16+m)*64 + s2*32 + quad*8);
        ob[ct] = MFMA_FH(ah, bw, ob[ct]);
      }
    }
    #pragma unroll
    for (int ct = 0; ct < 4; ct++) {
      const float b2v = b2[ct*16 + m];
      #pragma unroll
      for (int r = 0; r < 4; r++) {
        float v = fmaxf(ob[ct][r] + b2v, 0.f);
        h2f[(size_t)(r0 + quad*4 + r)*EMB + ct*16 + m] = (_Float16)v;
      }
    }
  }
}

// ---------------------------------------------------------------------------
// k3: GRU + logits via f16 MFMA. 16 rows/block, 512 blocks, 4 waves.
// ---------------------------------------------------------------------------
__global__ __launch_bounds__(256) void k3_gru(
    const float* __restrict__ beliefs, const _Float16* __restrict__ h2f,
    const u16* __restrict__ ctxp, const float* __restrict__ sums,
    const _Float16* __restrict__ WT,
    const float* __restrict__ bg, const float* __restrict__ bhr,
    const float* __restrict__ bhz, const float* __restrict__ bhn,
    const float* __restrict__ Wout, const float* __restrict__ bout,
    float* __restrict__ out)
{
  __shared__ _Float16 xf[16][136];     // x = [h2|ctx]; reused for new_beliefs
  __shared__ _Float16 belf[16][136];
  __shared__ _Float16 gruf[16][136];
  __shared__ float invs[16];
  const int t = threadIdx.x;
  const int lane = t & 63, wid = t >> 6;
  const int m = lane & 15, quad = lane >> 4;
  const int r0 = blockIdx.x * 16;

  {
    const int row = t >> 4, seg = t & 15;
    const float* bpR = beliefs + (size_t)(r0+row)*HID + seg*8;
    float4 a0 = *(const float4*)bpR;
    float4 a1 = *(const float4*)(bpR + 4);
    union { _Float16 e[8]; half8 v; } hb;
    hb.e[0]=(_Float16)a0.x; hb.e[1]=(_Float16)a0.y; hb.e[2]=(_Float16)a0.z; hb.e[3]=(_Float16)a0.w;
    hb.e[4]=(_Float16)a1.x; hb.e[5]=(_Float16)a1.y; hb.e[6]=(_Float16)a1.z; hb.e[7]=(_Float16)a1.w;
    *(half8*)&belf[row][seg*8] = hb.v;
  }
  float ctxa[8];
  const int crow = t >> 3, cdg = t & 7;
  if (t < 128) {
    half8 hv = *(const half8*)(h2f + (size_t)(r0+crow)*EMB + cdg*8);
    *(half8*)&xf[crow][cdg*8] = hv;
    #pragma unroll
    for (int d = 0; d < 8; d++) ctxa[d] = 0.f;
    #pragma unroll
    for (int sp = 0; sp < SPLIT; sp++) {
      uint4 u = *(const uint4*)(ctxp + ((size_t)sp*A_N + r0 + crow)*EMB + cdg*8);
      ctxa[0] += fval(u.x << 16); ctxa[1] += fval(u.x & 0xffff0000u);
      ctxa[2] += fval(u.y << 16); ctxa[3] += fval(u.y & 0xffff0000u);
      ctxa[4] += fval(u.z << 16); ctxa[5] += fval(u.z & 0xffff0000u);
      ctxa[6] += fval(u.w << 16); ctxa[7] += fval(u.w & 0xffff0000u);
    }
  }
  if (t < 16) {
    float s = 0.f;
    #pragma unroll
    for (int sp = 0; sp < SPLIT; sp++) s += sums[(size_t)sp*A_N + r0 + t];
    invs[t] = 1.f / s;
  }
  __syncthreads();
  if (t < 128) {
    const float iv = invs[crow];
    union { _Float16 e[8]; half8 v; } hc;
    #pragma unroll
    for (int d = 0; d < 8; d++) hc.e[d] = (_Float16)(ctxa[d] * iv);
    *(half8*)&xf[crow][64 + cdg*8] = hc.v;
  }
  __syncthreads();

  // Phase 1: gru_in = x @ Wg + bg
  f32x4 g[2];
  g[0] = (f32x4){0.f,0.f,0.f,0.f}; g[1] = (f32x4){0.f,0.f,0.f,0.f};
  #pragma unroll
  for (int s = 0; s < 4; s++) {
    half8 ax = *(const half8*)&xf[m][s*32 + quad*8];
    #pragma unroll
    for (int ci = 0; ci < 2; ci++) {
      const int ct = wid*2 + ci;
      half8 bw = *(const half8*)(WT + (size_t)(ct*16+m)*128 + s*32 + quad*8);
      g[ci] = MFMA_FH(ax, bw, g[ci]);
    }
  }
  #pragma unroll
  for (int ci = 0; ci < 2; ci++) {
    const int col = (wid*2+ci)*16 + m;
    const float bgv = bg[col];
    #pragma unroll
    for (int r = 0; r < 4; r++)
      gruf[quad*4+r][col] = (_Float16)(g[ci][r] + bgv);
  }
  __syncthreads();

  // Phase 2: gates
  f32x4 RV[2], ZV[2];
  #pragma unroll
  for (int gidx = 0; gidx < 3; gidx++) {
    const _Float16* WiTg = WT + (size_t)(1+gidx)*16384;
    const _Float16* WhTg = WT + (size_t)(4+gidx)*16384;
    f32x4 gi[2], gh[2];
    gi[0]=(f32x4){0.f,0.f,0.f,0.f}; gi[1]=(f32x4){0.f,0.f,0.f,0.f};
    gh[0]=(f32x4){0.f,0.f,0.f,0.f}; gh[1]=(f32x4){0.f,0.f,0.f,0.f};
    #pragma unroll
    for (int s = 0; s < 4; s++) {
      half8 ag = *(const half8*)&gruf[m][s*32 + quad*8];
      half8 ab = *(const half8*)&belf[m][s*32 + quad*8];
      #pragma unroll
      for (int ci = 0; ci < 2; ci++) {
        const int ct = wid*2 + ci;
        half8 bi = *(const half8*)(WiTg + (size_t)(ct*16+m)*128 + s*32 + quad*8);
        half8 bh = *(const half8*)(WhTg + (size_t)(ct*16+m)*128 + s*32 + quad*8);
        gi[ci] = MFMA_FH(ag, bi, gi[ci]);
        gh[ci] = MFMA_FH(ab, bh, gh[ci]);
      }
    }
    if (gidx == 0) {
      #pragma unroll
      for (int ci = 0; ci < 2; ci++) {
        const float bv = bhr[(wid*2+ci)*16 + m];
        #pragma unroll
        for (int r = 0; r < 4; r++) RV[ci][r] = sigmoidf_fast(gi[ci][r] + gh[ci][r] + bv);
      }
    } else if (gidx == 1) {
      #pragma unroll
      for (int ci = 0; ci < 2; ci++) {
        const float bv = bhz[(wid*2+ci)*16 + m];
        #pragma unroll
        for (int r = 0; r < 4; r++) ZV[ci][r] = sigmoidf_fast(gi[ci][r] + gh[ci][r] + bv);
      }
    } else {
      #pragma unroll
      for (int ci = 0; ci < 2; ci++) {
        const int col = (wid*2+ci)*16 + m;
        const float bv = bhn[col];
        #pragma unroll
        for (int r = 0; r < 4; r++) {
          const int row = quad*4 + r;
          float bel = beliefs[(size_t)(r0+row)*HID + col];
          float pre = gi[ci][r] + RV[ci][r] * (gh[ci][r] + bv);
          float nv = tanhf_fast(pre);
          float nb = (1.f - ZV[ci][r]) * nv + ZV[ci][r] * bel;
          out[(size_t)NACT*A_N + (size_t)(r0+row)*HID + col] = nb;
          xf[row][col] = (_Float16)nb;
        }
      }
    }
  }
  __syncthreads();

  // Phase 3: logits (Wout direct from global — L2-hot, 96 threads/block)
  if (t < 16*NACT) {
    const int row = t / NACT, c = t % NACT;
    float a = bout[c];
    #pragma unroll 8
    for (int k = 0; k < HID; k++)
      a += (float)xf[row][k] * Wout[(size_t)k*NACT + c];
    out[(size_t)(r0+row)*NACT + c] = a;
  }
}

// ---------------------------------------------------------------------------
extern "C" void kernel_launch(void* const* d_in, const int* in_sizes, int n_in,
                              void* d_out, int out_size, void* d_ws, size_t ws_size,
                              hipStream_t stream) {
  const float* obs     = (const float*)d_in[0];
  const float* beliefs = (const float*)d_in[1];
  const float* W1      = (const float*)d_in[2];
  const float* b1      = (const float*)d_in[3];
  const float* W2      = (const float*)d_in[4];
  const float* b2      = (const float*)d_in[5];
  const float* Wb      = (const float*)d_in[6];
  const float* bb      = (const float*)d_in[7];
  const float* Wg      = (const float*)d_in[8];
  const float* bg      = (const float*)d_in[9];
  const float* Wir     = (const float*)d_in[10];
  const float* Wiz     = (const float*)d_in[11];
  const float* Win     = (const float*)d_in[12];
  const float* Whr     = (const float*)d_in[13];
  const float* bhr     = (const float*)d_in[14];
  const float* Whz     = (const float*)d_in[15];
  const float* bhz     = (const float*)d_in[16];
  const float* Whn     = (const float*)d_in[17];
  const float* bhn     = (const float*)d_in[18];
  const float* Wout    = (const float*)d_in[19];
  const float* bout    = (const float*)d_in[20];
  float* out = (float*)d_out;

  // ws layout (bytes): h2f f16 1MB | bp 1MB | bpT 1MB | ctxp bf16 16MB |
  // sums f32 512KB | WT f16 224KB | W1T 68KB | W2T 8KB | WbT 16KB
  char* ws = (char*)d_ws;
  _Float16* h2f  = (_Float16*)(ws);
  u16*      bp   = (u16*)(ws + 1048576);
  u16*      bpT  = (u16*)(ws + 2097152);
  u16*      ctxp = (u16*)(ws + 3145728);
  float*    sums = (float*)(ws + 19922944);
  _Float16* WT   = (_Float16*)(ws + 20447232);
  _Float16* W1T  = (_Float16*)(ws + 20676608);
  _Float16* W2T  = (_Float16*)(ws + 20746240);
  u16*      WbT  = (u16*)(ws + 20754432);

  hipLaunchKernelGGL(kPrep, dim3(40), dim3(256), 0, stream,
                     Wg, Wir, Wiz, Win, Whr, Whz, Whn, W1, W2, Wb, WT, W1T, W2T, WbT);
  hipLaunchKernelGGL(kA2, dim3(128), dim3(256), 0, stream, beliefs, WbT, bb, bp, bpT);
  hipLaunchKernelGGL(kM, dim3(1152), dim3(256), 0, stream,
                     bp, bpT, ctxp, sums, obs, W1T, b1, W2T, b2, h2f);
  hipLaunchKernelGGL(k3_gru, dim3(512), dim3(256), 0, stream,
                     beliefs, h2f, ctxp, sums, WT, bg, bhr, bhz, bhn, Wout, bout, out);
}